// Round 17
// baseline (650.868 us; speedup 1.0000x reference)
//
#include <hip/hip_runtime.h>
#include <hip/hip_bf16.h>

#define DMODEL 1024
#define DINNER 2048
#define DSTATE 64
#define BATCH 2
#define SEQLEN 4096
#define NROWS (BATCH*SEQLEN)          // 8192
#define DTN 144                        // NHEADS + 2*DSTATE
#define CHUNK 64
#define NCHUNK (SEQLEN/CHUNK)          // 64

typedef unsigned short u16;
typedef unsigned int u32;
typedef __attribute__((ext_vector_type(8))) short bf16x8;
typedef __attribute__((ext_vector_type(4))) float f32x4;
typedef __attribute__((ext_vector_type(4))) u32 u32x4;

__device__ __forceinline__ float b2f(u16 u){ u32 i = ((u32)u)<<16; return __builtin_bit_cast(float, i); }
__device__ __forceinline__ u16 f2b(float f){ u32 i = __builtin_bit_cast(u32, f); u32 r = (i + 0x7FFFu + ((i>>16)&1u))>>16; return (u16)r; }
__device__ __forceinline__ float silu_f(float x){ return x / (1.f + __expf(-x)); }
__device__ __forceinline__ float fexp2(float x){ float r; asm("v_exp_f32 %0, %1" : "=v"(r) : "v"(x)); return r; }

__device__ __forceinline__ void gload16(const u16* g, u16* l){
    __builtin_amdgcn_global_load_lds((const __attribute__((address_space(1))) void*)g,
                                     (__attribute__((address_space(3))) void*)l, 16, 0, 0);
}

// ---------------- cast fp32 -> bf16 ----------------
__global__ __launch_bounds__(256) void cast_k(const float* __restrict__ in, u16* __restrict__ out, int n){
    int i = (blockIdx.x*256 + threadIdx.x)*8;
    if (i + 8 > n) return;
    f32x4 a = *(const f32x4*)(in + i);
    f32x4 b = *(const f32x4*)(in + i + 4);
    bf16x8 o;
    o[0]=(short)f2b(a[0]); o[1]=(short)f2b(a[1]); o[2]=(short)f2b(a[2]); o[3]=(short)f2b(a[3]);
    o[4]=(short)f2b(b[0]); o[5]=(short)f2b(b[1]); o[6]=(short)f2b(b[2]); o[7]=(short)f2b(b[3]);
    *(bf16x8*)(out + i) = o;
}

// ---------------- A2 pack (bf16 pairs, for scanB) ----------------
__global__ __launch_bounds__(256) void a2pack_k(const float* __restrict__ Alog, u32* __restrict__ A2v){
    int i = blockIdx.x*256 + threadIdx.x;     // < 16384
    int d = i & 2047, k4 = i >> 11;
    u32x4 o;
    #pragma unroll
    for (int j=0;j<4;++j){
        int n0 = (k4*4+j)*2;
        float a0 = -__expf(Alog[(long)d*64 + n0    ]) * 1.44269504f;
        float a1 = -__expf(Alog[(long)d*64 + n0 + 1]) * 1.44269504f;
        o[j] = (u32)f2b(a0) | ((u32)f2b(a1)<<16);
    }
    *(u32x4*)(A2v + ((long)k4*2048 + d)*4) = o;
}

// ---------------- A2 expanded f32, transposed: A2f[n][d] = -exp(A_log[d][n])*log2e ----------------
__global__ __launch_bounds__(256) void a2packf_k(const float* __restrict__ Alog, float* __restrict__ A2f){
    int i = blockIdx.x*256 + threadIdx.x;     // < 131072
    int n = i >> 11, d = i & 2047;
    A2f[i] = -__expf(Alog[(long)d*64 + n]) * 1.44269504f;
}

// ---------------- xpf init: broadcast dt_proj bias into every row ----------------
__global__ __launch_bounds__(256) void xpinit_k(float* __restrict__ xpf, const float* __restrict__ bias){
    int i = blockIdx.x*256 + threadIdx.x;        // < NROWS*DTN
    if (i >= NROWS*DTN) return;
    xpf[i] = bias[i % DTN];
}

// ---------------- split-K skinny GEMM (64x64 tile, blockIdx.z = K-slice), atomicAdd epilogue ----------------
__global__ __launch_bounds__(256) void gemmsk_k(
    const u16* __restrict__ A, const u16* __restrict__ B,
    float* __restrict__ Cf, int M, int N, int K, int klen)
{
    __shared__ u16 lA[64][72];
    __shared__ u16 lB[64][72];
    int tid = threadIdx.x;
    int bm = blockIdx.y, bn = blockIdx.x;
    int kbase = blockIdx.z * klen;
    int wave = tid>>6, lane = tid&63;
    int wr = wave>>1, wc = wave&1;
    f32x4 acc[2][2];
    #pragma unroll
    for (int r=0;r<2;++r)
    #pragma unroll
    for (int c=0;c<2;++c) acc[r][c] = 0.f;

    int lr = tid>>3;
    int lc = (tid&7)*8;
    long arow0 = (long)(bm*64 + lr)*K;
    long arow1 = (long)(bm*64 + lr + 32)*K;
    int brow0 = bn*64 + lr, brow1 = brow0 + 32;

    for (int k0 = kbase; k0 < kbase + klen; k0 += 64){
        __syncthreads();
        *(bf16x8*)&lA[lr][lc]    = *(const bf16x8*)(A + arow0 + k0 + lc);
        *(bf16x8*)&lA[lr+32][lc] = *(const bf16x8*)(A + arow1 + k0 + lc);
        bf16x8 b0 = 0, b1 = 0;
        if (brow0 < N) b0 = *(const bf16x8*)(B + (long)brow0*K + k0 + lc);
        if (brow1 < N) b1 = *(const bf16x8*)(B + (long)brow1*K + k0 + lc);
        *(bf16x8*)&lB[lr][lc]    = b0;
        *(bf16x8*)&lB[lr+32][lc] = b1;
        __syncthreads();
        int rA0 = wr*32 + (lane&15);
        int cB0 = wc*32 + (lane&15);
        int kl  = (lane>>4)*8;
        #pragma unroll
        for (int kk = 0; kk < 64; kk += 32){
            bf16x8 a0 = *(const bf16x8*)&lA[rA0   ][kk+kl];
            bf16x8 a1 = *(const bf16x8*)&lA[rA0+16][kk+kl];
            bf16x8 v0 = *(const bf16x8*)&lB[cB0   ][kk+kl];
            bf16x8 v1 = *(const bf16x8*)&lB[cB0+16][kk+kl];
            acc[0][0] = __builtin_amdgcn_mfma_f32_16x16x32_bf16(a0, v0, acc[0][0], 0,0,0);
            acc[0][1] = __builtin_amdgcn_mfma_f32_16x16x32_bf16(a0, v1, acc[0][1], 0,0,0);
            acc[1][0] = __builtin_amdgcn_mfma_f32_16x16x32_bf16(a1, v0, acc[1][0], 0,0,0);
            acc[1][1] = __builtin_amdgcn_mfma_f32_16x16x32_bf16(a1, v1, acc[1][1], 0,0,0);
        }
    }
    #pragma unroll
    for (int r=0;r<2;++r){
        #pragma unroll
        for (int c=0;c<2;++c){
            int col = bn*64 + wc*32 + c*16 + (lane&15);
            if (col >= N) continue;
            #pragma unroll
            for (int e=0;e<4;++e){
                int row = bm*64 + wr*32 + r*16 + (lane>>4)*4 + e;
                atomicAdd(&Cf[(long)row*N + col], acc[r][c][e]);
            }
        }
    }
}

// ---------------- m97-style 128x128 GEMM + XCD-aware block swizzle ----------------
__global__ __launch_bounds__(256) void gemm128_k(
    const u16* __restrict__ A, const u16* __restrict__ B,
    float* __restrict__ Cf, u16* __restrict__ Cb0, u16* __restrict__ Cb1, int split,
    int M, int N, int K)
{
    __shared__ u16 lA[128*64];
    __shared__ u16 lB[128*64];
    int tid = threadIdx.x, wave = tid>>6, lane = tid&63;
    int nwgx = gridDim.x;
    int flat = blockIdx.y*nwgx + blockIdx.x;
    int q = (nwgx*gridDim.y) >> 3;
    int nf = (flat & 7)*q + (flat >> 3);
    int bn = nf % nwgx, bm = nf / nwgx;
    int wr = wave>>1, wc = wave&1;
    f32x4 acc[4][4];
    #pragma unroll
    for (int i=0;i<4;++i)
    #pragma unroll
    for (int j=0;j<4;++j) acc[i][j] = 0.f;

    int srow = lane>>3;
    int scol = (lane&7)*8;
    const u16* Abase = A + (long)(bm*128)*K;
    const u16* Bbase = B + (long)(bn*128)*K;

    for (int k0 = 0; k0 < K; k0 += 64){
        __syncthreads();
        #pragma unroll
        for (int i=0;i<4;++i){
            int qq = i*4 + wave;
            int r = qq*8 + srow;
            gload16(Abase + (long)r*K + k0 + scol, &lA[qq*512]);
            gload16(Bbase + (long)r*K + k0 + scol, &lB[qq*512]);
        }
        __syncthreads();
        #pragma unroll
        for (int kk=0; kk<64; kk+=32){
            int kb = kk + ((lane>>4)<<3);
            bf16x8 af[4], bfr[4];
            #pragma unroll
            for (int i=0;i<4;++i) af[i]  = *(const bf16x8*)&lA[(wr*64 + i*16 + (lane&15))*64 + kb];
            #pragma unroll
            for (int j=0;j<4;++j) bfr[j] = *(const bf16x8*)&lB[(wc*64 + j*16 + (lane&15))*64 + kb];
            #pragma unroll
            for (int i=0;i<4;++i)
            #pragma unroll
            for (int j=0;j<4;++j)
                acc[i][j] = __builtin_amdgcn_mfma_f32_16x16x32_bf16(af[i], bfr[j], acc[i][j], 0,0,0);
        }
    }
    #pragma unroll
    for (int i=0;i<4;++i){
        #pragma unroll
        for (int j=0;j<4;++j){
            int col = bn*128 + wc*64 + j*16 + (lane&15);
            #pragma unroll
            for (int e=0;e<4;++e){
                int row = bm*128 + wr*64 + i*16 + (lane>>4)*4 + e;
                float v = acc[i][j][e];
                if (Cb0){
                    if (col < split) Cb0[(long)row*split + col] = f2b(v);
                    else             Cb1[(long)row*split + (col-split)] = f2b(v);
                } else {
                    Cf[(long)row*N + col] = v;
                }
            }
        }
    }
}

// ---------------- depthwise conv, 8 rows/block ----------------
__global__ __launch_bounds__(256) void conv2_k(
    const u16* __restrict__ xb, const float* __restrict__ cw, const float* __restrict__ cb,
    u16* __restrict__ ub)
{
    int rb = blockIdx.x;
    int t0g = rb*8;
    int b = t0g >> 12, t0 = t0g & 4095;
    int d0 = threadIdx.x * 8;
    float w[4][8];
    #pragma unroll
    for (int e=0;e<8;++e){
        f32x4 wv = *(const f32x4*)(cw + (d0+e)*4);
        w[0][e]=wv[0]; w[1][e]=wv[1]; w[2][e]=wv[2]; w[3][e]=wv[3];
    }
    float bias[8];
    #pragma unroll
    for (int e=0;e<8;++e) bias[e] = cb[d0+e];

    bf16x8 xr[11];
    #pragma unroll
    for (int r=0;r<11;++r){
        int tr = t0 - 3 + r;
        bf16x8 v = 0;
        if (tr >= 0 && r < 8+3) v = *(const bf16x8*)(xb + ((long)(b*4096 + tr))*2048 + d0);
        xr[r] = v;
    }
    #pragma unroll
    for (int r=0;r<8;++r){
        bf16x8 o;
        #pragma unroll
        for (int e=0;e<8;++e){
            float acc = bias[e];
            #pragma unroll
            for (int j=0;j<4;++j) acc += b2f((u16)xr[r+j][e]) * w[j][e];
            o[e] = (short)f2b(silu_f(acc));
        }
        *(bf16x8*)(ub + ((long)(t0g + r))*2048 + d0) = o;
    }
}

// ---------------- dt softplus ----------------
__global__ __launch_bounds__(256) void dtv_k(const float* __restrict__ xp, const float* __restrict__ dtb, float* __restrict__ dtv){
    int i = blockIdx.x*256 + threadIdx.x;
    int row = i >> 4, h = i & 15;
    float x = xp[(long)row*DTN + h] + dtb[h];
    float sp = (x > 15.f) ? x : __logf(1.f + __expf(x));
    dtv[i] = sp;
}

// ---------------- scan phase A: split-n, f32 A2, unroll-2 t-loop ----------------
__global__ __launch_bounds__(256) void scanA11_k(
    const u16* __restrict__ ub, const float* __restrict__ dtv,
    const float* __restrict__ xpf, const float* __restrict__ A2f,
    u16* __restrict__ states, float* __restrict__ dtsum)
{
    __shared__ u16 uL[CHUNK][256];        // 32 KB
    int blk = blockIdx.x;                 // ((b*NCHUNK+c)*16 + g*2 + nh)
    int g2 = blk & 15; int g = g2 >> 1; int nh = g2 & 1;
    int bc = blk >> 4; int c = bc & (NCHUNK-1); int b = bc >> 6;
    int tid = threadIdx.x;
    int d = g*256 + tid;
    int n0 = nh*32;
    int base = b*SEQLEN + c*CHUNK;
    int h = __builtin_amdgcn_readfirstlane(g*2 + ((tid>>7)&1));

    for (int i = tid; i < CHUNK*32; i += 256){
        int t = i >> 5, seg = i & 31;
        *(bf16x8*)&uL[t][seg*8] = *(const bf16x8*)(ub + (long)(base+t)*2048 + g*256 + seg*8);
    }
    __syncthreads();

    float A2[32];
    #pragma unroll
    for (int j=0;j<32;++j) A2[j] = A2f[(long)(n0+j)*2048 + d];

    float s[32];
    #pragma unroll
    for (int n=0;n<32;++n) s[n] = 0.f;
    float dts = 0.f;
    #pragma unroll 2
    for (int t=0;t<CHUNK;++t){
        int row = __builtin_amdgcn_readfirstlane(base + t);
        const float* xr = xpf + (long)row*DTN + 16 + n0;  // B half (uniform -> s_load)
        float dtc = dtv[row*16 + h];                       // uniform -> s_load
        float uu = b2f(uL[t][tid]);
        float dtu = dtc*uu;
        dts += dtc;
        #pragma unroll
        for (int n=0;n<32;++n){
            float e = fexp2(dtc*A2[n]);
            s[n] = fmaf(s[n], e, dtu*xr[n]);
        }
    }
    long sb = ((long)((b*NCHUNK + c)*64) + n0)*2048 + d;
    #pragma unroll
    for (int n=0;n<32;++n) states[sb + (long)n*2048] = f2b(s[n]);
    if (nh == 0) dtsum[(long)(b*NCHUNK+c)*2048 + d] = dts;
}

// ---------------- scan phase B: prefix-combine over chunks (in-place, bf16 states) ----------------
__global__ __launch_bounds__(256) void scanB8_k(
    u16* __restrict__ states, const float* __restrict__ dtsum, const u32* __restrict__ A2v)
{
    int idx = blockIdx.x*256 + threadIdx.x;
    int b = idx >> 17;
    int r = idx & 131071;
    int n = r >> 11; int d = r & 2047;
    u32 pk = A2v[((long)(n>>3)*2048 + d)*4 + ((n>>1)&3)];
    float A2 = (n&1) ? __builtin_bit_cast(float, pk & 0xFFFF0000u)
                     : __builtin_bit_cast(float, pk<<16);
    float carry = 0.f;
    for (int c=0;c<NCHUNK;++c){
        long off = ((long)((b*NCHUNK+c)*64 + n))*2048 + d;
        float loc = b2f(states[off]);
        states[off] = f2b(carry);
        float ds = dtsum[(long)(b*NCHUNK+c)*2048 + d];
        carry = carry*fexp2(A2*ds) + loc;
    }
}

// ---------------- scan phase C: split-n, f32 A2, two sequential launches ----------------
__global__ __launch_bounds__(256) void scanC11_k(
    const u16* __restrict__ ub, const float* __restrict__ dtv,
    const float* __restrict__ xpf, const float* __restrict__ A2f,
    const u16* __restrict__ states, const float* __restrict__ Dv,
    u16* __restrict__ Y, int nh)
{
    __shared__ u16 uL[CHUNK][256];        // 32 KB
    int blk = blockIdx.x;
    int g = blk & 7; int bc = blk >> 3; int c = bc & (NCHUNK-1); int b = bc >> 6;
    int tid = threadIdx.x;
    int d = g*256 + tid;
    int n0 = nh*32;
    int base = b*SEQLEN + c*CHUNK;
    int h = __builtin_amdgcn_readfirstlane(g*2 + ((tid>>7)&1));

    for (int i = tid; i < CHUNK*32; i += 256){
        int t = i >> 5, seg = i & 31;
        *(bf16x8*)&uL[t][seg*8] = *(const bf16x8*)(ub + (long)(base+t)*2048 + g*256 + seg*8);
    }
    __syncthreads();

    float A2[32];
    #pragma unroll
    for (int j=0;j<32;++j) A2[j] = A2f[(long)(n0+j)*2048 + d];

    float s[32];
    long sb = ((long)((b*NCHUNK + c)*64) + n0)*2048 + d;
    #pragma unroll
    for (int n=0;n<32;++n) s[n] = b2f(states[sb + (long)n*2048]);
    float Dd = Dv[d];
    for (int t=0;t<CHUNK;++t){
        int row = __builtin_amdgcn_readfirstlane(base + t);
        const float* xr = xpf + (long)row*DTN + 16 + n0;  // B half (uniform)
        const float* xc = xr + 64;                         // C half (uniform)
        float dtc = dtv[row*16 + h];
        float uu = b2f(uL[t][tid]);
        float dtu = dtc*uu;
        float y0=0.f, y1=0.f;
        #pragma unroll
        for (int n=0;n<32;n+=2){
            float e0 = fexp2(dtc*A2[n]);
            float e1 = fexp2(dtc*A2[n+1]);
            s[n]   = fmaf(s[n],   e0, dtu*xr[n]);
            s[n+1] = fmaf(s[n+1], e1, dtu*xr[n+1]);
            y0 = fmaf(s[n],   xc[n],   y0);
            y1 = fmaf(s[n+1], xc[n+1], y1);
        }
        float y = y0 + y1;
        long yoff = (long)row*2048 + d;
        if (nh == 0){
            Y[yoff] = f2b(y);
        } else {
            y += b2f(Y[yoff]);
            Y[yoff] = f2b(fmaf(uu, Dd, y));
        }
    }
}

// ---------------- gate (y * silu(z)) + LayerNorm, in-place over Y (bf16) ----------------
__global__ __launch_bounds__(256) void gatenorm_k(
    u16* __restrict__ Y, const u16* __restrict__ zb,
    const float* __restrict__ nw, const float* __restrict__ nb)
{
    int row = blockIdx.x;
    int tid = threadIdx.x;
    int d0 = tid*8;
    bf16x8 zv = *(const bf16x8*)(zb + (long)row*2048 + d0);
    bf16x8 yv = *(const bf16x8*)(Y + (long)row*2048 + d0);
    float gv[8];
    #pragma unroll
    for (int e=0;e<8;++e){
        float y = b2f((u16)yv[e]);
        float z = b2f((u16)zv[e]);
        gv[e] = y * silu_f(z);
    }
    float s1=0.f, s2=0.f;
    #pragma unroll
    for (int e=0;e<8;++e){ s1 += gv[e]; s2 += gv[e]*gv[e]; }
    #pragma unroll
    for (int o=32;o>0;o>>=1){ s1 += __shfl_xor(s1,o,64); s2 += __shfl_xor(s2,o,64); }
    __shared__ float red[2][4];
    int wave = tid>>6, lane = tid&63;
    if (lane==0){ red[0][wave]=s1; red[1][wave]=s2; }
    __syncthreads();
    s1 = red[0][0]+red[0][1]+red[0][2]+red[0][3];
    s2 = red[1][0]+red[1][1]+red[1][2]+red[1][3];
    float mu = s1 * (1.f/2048.f);
    float var = s2 * (1.f/2048.f) - mu*mu;
    float rs = rsqrtf(var + 1e-5f);
    bf16x8 o;
    #pragma unroll
    for (int e=0;e<8;++e){
        float v = (gv[e]-mu)*rs*nw[d0+e] + nb[d0+e];
        o[e] = (short)f2b(v);
    }
    *(bf16x8*)(Y + (long)row*2048 + d0) = o;
}

extern "C" void kernel_launch(void* const* d_in, const int* in_sizes, int n_in,
                              void* d_out, int out_size, void* d_ws, size_t ws_size,
                              hipStream_t stream)
{
    const float* hidden = (const float*)d_in[0];
    const float* w_in   = (const float*)d_in[1];
    const float* conv_w = (const float*)d_in[2];
    const float* conv_b = (const float*)d_in[3];
    const float* w_dt   = (const float*)d_in[4];
    const float* b_dt   = (const float*)d_in[5];
    const float* dt_bias= (const float*)d_in[6];
    const float* A_log  = (const float*)d_in[7];
    const float* Dv     = (const float*)d_in[8];
    const float* norm_w = (const float*)d_in[9];
    const float* norm_b = (const float*)d_in[10];
    const float* w_out  = (const float*)d_in[11];

    char* ws = (char*)d_ws;

    const size_t SZ_hb   = (size_t)NROWS*DMODEL*2;
    const size_t SZ_wib  = (size_t)2*DINNER*DMODEL*2;
    const size_t SZ_regA = SZ_hb + SZ_wib;
    const size_t SZ_big  = (size_t)NROWS*DINNER*2;
    const size_t SZ_wdtb = (size_t)DTN*DINNER*2;
    const size_t SZ_xpf  = (size_t)NROWS*DTN*4;
    const size_t SZ_dtv  = (size_t)NROWS*16*4;
    const size_t SZ_A2   = (size_t)DINNER*32*4;
    const size_t SZ_A2f  = (size_t)DINNER*DSTATE*4;
    const size_t SZ_states = (size_t)BATCH*NCHUNK*DSTATE*DINNER*2;
    const size_t SZ_dtsum  = (size_t)BATCH*NCHUNK*DINNER*4;

    size_t off = 0;
    auto take = [&](size_t bytes)->char*{ char* p = ws + off; off += (bytes + 255) & ~(size_t)255; return p; };

    char* regA = take(SZ_regA);
    u16*  hb   = (u16*)regA;
    u16*  wib  = (u16*)(regA + SZ_hb);
    u16*  wdtb = (u16*)regA;                                  // after in_proj
    u16*  wob  = (u16*)(regA + ((SZ_wdtb + 255) & ~(size_t)255));
    u16*  xb   = (u16*)take(SZ_big);                          // x; Y aliases after conv
    u16*  zb   = (u16*)take(SZ_big);
    u16*  ub   = (u16*)take(SZ_big);
    float* xpf = (float*)take(SZ_xpf);
    float* dtv = (float*)take(SZ_dtv);
    u32*  A2v  = (u32*)take(SZ_A2);
    float* A2f = (float*)take(SZ_A2f);
    u16*  states = (u16*)take(SZ_states);
    float* dtsum  = (float*)take(SZ_dtsum);
    u16*  Y    = xb;
    if (off > ws_size) return;

    { int n = NROWS*DMODEL;       cast_k<<<dim3((n/8+255)/256), dim3(256), 0, stream>>>(hidden, hb, n); }
    { int n = 2*DINNER*DMODEL;    cast_k<<<dim3((n/8+255)/256), dim3(256), 0, stream>>>(w_in, wib, n); }
    a2pack_k<<<dim3(DINNER*8/256), dim3(256), 0, stream>>>(A_log, A2v);
    a2packf_k<<<dim3(DINNER*DSTATE/256), dim3(256), 0, stream>>>(A_log, A2f);

    gemm128_k<<<dim3((2*DINNER)/128, NROWS/128), dim3(256), 0, stream>>>(hb, wib, nullptr, xb, zb, DINNER, NROWS, 2*DINNER, DMODEL);

    { int n = DTN*DINNER;         cast_k<<<dim3((n/8+255)/256), dim3(256), 0, stream>>>(w_dt, wdtb, n); }
    { int n = DMODEL*DINNER;      cast_k<<<dim3((n/8+255)/256), dim3(256), 0, stream>>>(w_out, wob, n); }

    conv2_k<<<dim3(NROWS/8), dim3(256), 0, stream>>>(xb, conv_w, conv_b, ub);
    xpinit_k<<<dim3((NROWS*DTN + 255)/256), dim3(256), 0, stream>>>(xpf, b_dt);
    gemmsk_k<<<dim3((DTN+63)/64, NROWS/64, 4), dim3(256), 0, stream>>>(ub, wdtb, xpf, NROWS, DTN, DINNER, DINNER/4);
    dtv_k<<<dim3(NROWS*16/256), dim3(256), 0, stream>>>(xpf, dt_bias, dtv);

    scanA11_k<<<dim3(BATCH*NCHUNK*16), dim3(256), 0, stream>>>(ub, dtv, xpf, A2f, states, dtsum);
    scanB8_k<<<dim3(BATCH*DSTATE*DINNER/256), dim3(256), 0, stream>>>(states, dtsum, A2v);
    scanC11_k<<<dim3(BATCH*NCHUNK*8), dim3(256), 0, stream>>>(ub, dtv, xpf, A2f, states, Dv, Y, 0);
    scanC11_k<<<dim3(BATCH*NCHUNK*8), dim3(256), 0, stream>>>(ub, dtv, xpf, A2f, states, Dv, Y, 1);

    gatenorm_k<<<dim3(NROWS), dim3(256), 0, stream>>>(Y, zb, norm_w, norm_b);
    gemm128_k<<<dim3(DMODEL/128, NROWS/128), dim3(256), 0, stream>>>(Y, wob, (float*)d_out, nullptr, nullptr, 0, NROWS, DMODEL, DINNER);
}

// Round 18
// 598.345 us; speedup vs baseline: 1.0878x; 1.0878x over previous
//
#include <hip/hip_runtime.h>
#include <hip/hip_bf16.h>

#define DMODEL 1024
#define DINNER 2048
#define DSTATE 64
#define BATCH 2
#define SEQLEN 4096
#define NROWS (BATCH*SEQLEN)          // 8192
#define DTN 144                        // NHEADS + 2*DSTATE
#define CHUNK 64
#define NCHUNK (SEQLEN/CHUNK)          // 64

typedef unsigned short u16;
typedef unsigned int u32;
typedef __attribute__((ext_vector_type(8))) short bf16x8;
typedef __attribute__((ext_vector_type(4))) float f32x4;
typedef __attribute__((ext_vector_type(4))) u32 u32x4;

__device__ __forceinline__ float b2f(u16 u){ u32 i = ((u32)u)<<16; return __builtin_bit_cast(float, i); }
__device__ __forceinline__ u16 f2b(float f){ u32 i = __builtin_bit_cast(u32, f); u32 r = (i + 0x7FFFu + ((i>>16)&1u))>>16; return (u16)r; }
__device__ __forceinline__ float silu_f(float x){ return x / (1.f + __expf(-x)); }
__device__ __forceinline__ float fexp2(float x){ float r; asm("v_exp_f32 %0, %1" : "=v"(r) : "v"(x)); return r; }

__device__ __forceinline__ void gload16(const u16* g, u16* l){
    __builtin_amdgcn_global_load_lds((const __attribute__((address_space(1))) void*)g,
                                     (__attribute__((address_space(3))) void*)l, 16, 0, 0);
}

// ---------------- cast fp32 -> bf16 ----------------
__global__ __launch_bounds__(256) void cast_k(const float* __restrict__ in, u16* __restrict__ out, int n){
    int i = (blockIdx.x*256 + threadIdx.x)*8;
    if (i + 8 > n) return;
    f32x4 a = *(const f32x4*)(in + i);
    f32x4 b = *(const f32x4*)(in + i + 4);
    bf16x8 o;
    o[0]=(short)f2b(a[0]); o[1]=(short)f2b(a[1]); o[2]=(short)f2b(a[2]); o[3]=(short)f2b(a[3]);
    o[4]=(short)f2b(b[0]); o[5]=(short)f2b(b[1]); o[6]=(short)f2b(b[2]); o[7]=(short)f2b(b[3]);
    *(bf16x8*)(out + i) = o;
}

// ---------------- A2 pack (bf16 pairs, for scanB) ----------------
__global__ __launch_bounds__(256) void a2pack_k(const float* __restrict__ Alog, u32* __restrict__ A2v){
    int i = blockIdx.x*256 + threadIdx.x;     // < 16384
    int d = i & 2047, k4 = i >> 11;
    u32x4 o;
    #pragma unroll
    for (int j=0;j<4;++j){
        int n0 = (k4*4+j)*2;
        float a0 = -__expf(Alog[(long)d*64 + n0    ]) * 1.44269504f;
        float a1 = -__expf(Alog[(long)d*64 + n0 + 1]) * 1.44269504f;
        o[j] = (u32)f2b(a0) | ((u32)f2b(a1)<<16);
    }
    *(u32x4*)(A2v + ((long)k4*2048 + d)*4) = o;
}

// ---------------- A2 expanded f32, transposed: A2f[n][d] ----------------
__global__ __launch_bounds__(256) void a2packf_k(const float* __restrict__ Alog, float* __restrict__ A2f){
    int i = blockIdx.x*256 + threadIdx.x;     // < 131072
    int n = i >> 11, d = i & 2047;
    A2f[i] = -__expf(Alog[(long)d*64 + n]) * 1.44269504f;
}

// ---------------- xpf init: broadcast dt_proj bias into every row ----------------
__global__ __launch_bounds__(256) void xpinit_k(float* __restrict__ xpf, const float* __restrict__ bias){
    int i = blockIdx.x*256 + threadIdx.x;        // < NROWS*DTN
    if (i >= NROWS*DTN) return;
    xpf[i] = bias[i % DTN];
}

// ---------------- split-K skinny GEMM (64x64 tile, blockIdx.z = K-slice), atomicAdd epilogue ----------------
__global__ __launch_bounds__(256) void gemmsk_k(
    const u16* __restrict__ A, const u16* __restrict__ B,
    float* __restrict__ Cf, int M, int N, int K, int klen)
{
    __shared__ u16 lA[64][72];
    __shared__ u16 lB[64][72];
    int tid = threadIdx.x;
    int bm = blockIdx.y, bn = blockIdx.x;
    int kbase = blockIdx.z * klen;
    int wave = tid>>6, lane = tid&63;
    int wr = wave>>1, wc = wave&1;
    f32x4 acc[2][2];
    #pragma unroll
    for (int r=0;r<2;++r)
    #pragma unroll
    for (int c=0;c<2;++c) acc[r][c] = 0.f;

    int lr = tid>>3;
    int lc = (tid&7)*8;
    long arow0 = (long)(bm*64 + lr)*K;
    long arow1 = (long)(bm*64 + lr + 32)*K;
    int brow0 = bn*64 + lr, brow1 = brow0 + 32;

    for (int k0 = kbase; k0 < kbase + klen; k0 += 64){
        __syncthreads();
        *(bf16x8*)&lA[lr][lc]    = *(const bf16x8*)(A + arow0 + k0 + lc);
        *(bf16x8*)&lA[lr+32][lc] = *(const bf16x8*)(A + arow1 + k0 + lc);
        bf16x8 b0 = 0, b1 = 0;
        if (brow0 < N) b0 = *(const bf16x8*)(B + (long)brow0*K + k0 + lc);
        if (brow1 < N) b1 = *(const bf16x8*)(B + (long)brow1*K + k0 + lc);
        *(bf16x8*)&lB[lr][lc]    = b0;
        *(bf16x8*)&lB[lr+32][lc] = b1;
        __syncthreads();
        int rA0 = wr*32 + (lane&15);
        int cB0 = wc*32 + (lane&15);
        int kl  = (lane>>4)*8;
        #pragma unroll
        for (int kk = 0; kk < 64; kk += 32){
            bf16x8 a0 = *(const bf16x8*)&lA[rA0   ][kk+kl];
            bf16x8 a1 = *(const bf16x8*)&lA[rA0+16][kk+kl];
            bf16x8 v0 = *(const bf16x8*)&lB[cB0   ][kk+kl];
            bf16x8 v1 = *(const bf16x8*)&lB[cB0+16][kk+kl];
            acc[0][0] = __builtin_amdgcn_mfma_f32_16x16x32_bf16(a0, v0, acc[0][0], 0,0,0);
            acc[0][1] = __builtin_amdgcn_mfma_f32_16x16x32_bf16(a0, v1, acc[0][1], 0,0,0);
            acc[1][0] = __builtin_amdgcn_mfma_f32_16x16x32_bf16(a1, v0, acc[1][0], 0,0,0);
            acc[1][1] = __builtin_amdgcn_mfma_f32_16x16x32_bf16(a1, v1, acc[1][1], 0,0,0);
        }
    }
    #pragma unroll
    for (int r=0;r<2;++r){
        #pragma unroll
        for (int c=0;c<2;++c){
            int col = bn*64 + wc*32 + c*16 + (lane&15);
            if (col >= N) continue;
            #pragma unroll
            for (int e=0;e<4;++e){
                int row = bm*64 + wr*32 + r*16 + (lane>>4)*4 + e;
                atomicAdd(&Cf[(long)row*N + col], acc[r][c][e]);
            }
        }
    }
}

// ---------------- m97-style 128x128 GEMM + XCD-aware block swizzle ----------------
__global__ __launch_bounds__(256) void gemm128_k(
    const u16* __restrict__ A, const u16* __restrict__ B,
    float* __restrict__ Cf, u16* __restrict__ Cb0, u16* __restrict__ Cb1, int split,
    int M, int N, int K)
{
    __shared__ u16 lA[128*64];
    __shared__ u16 lB[128*64];
    int tid = threadIdx.x, wave = tid>>6, lane = tid&63;
    int nwgx = gridDim.x;
    int flat = blockIdx.y*nwgx + blockIdx.x;
    int q = (nwgx*gridDim.y) >> 3;
    int nf = (flat & 7)*q + (flat >> 3);
    int bn = nf % nwgx, bm = nf / nwgx;
    int wr = wave>>1, wc = wave&1;
    f32x4 acc[4][4];
    #pragma unroll
    for (int i=0;i<4;++i)
    #pragma unroll
    for (int j=0;j<4;++j) acc[i][j] = 0.f;

    int srow = lane>>3;
    int scol = (lane&7)*8;
    const u16* Abase = A + (long)(bm*128)*K;
    const u16* Bbase = B + (long)(bn*128)*K;

    for (int k0 = 0; k0 < K; k0 += 64){
        __syncthreads();
        #pragma unroll
        for (int i=0;i<4;++i){
            int qq = i*4 + wave;
            int r = qq*8 + srow;
            gload16(Abase + (long)r*K + k0 + scol, &lA[qq*512]);
            gload16(Bbase + (long)r*K + k0 + scol, &lB[qq*512]);
        }
        __syncthreads();
        #pragma unroll
        for (int kk=0; kk<64; kk+=32){
            int kb = kk + ((lane>>4)<<3);
            bf16x8 af[4], bfr[4];
            #pragma unroll
            for (int i=0;i<4;++i) af[i]  = *(const bf16x8*)&lA[(wr*64 + i*16 + (lane&15))*64 + kb];
            #pragma unroll
            for (int j=0;j<4;++j) bfr[j] = *(const bf16x8*)&lB[(wc*64 + j*16 + (lane&15))*64 + kb];
            #pragma unroll
            for (int i=0;i<4;++i)
            #pragma unroll
            for (int j=0;j<4;++j)
                acc[i][j] = __builtin_amdgcn_mfma_f32_16x16x32_bf16(af[i], bfr[j], acc[i][j], 0,0,0);
        }
    }
    #pragma unroll
    for (int i=0;i<4;++i){
        #pragma unroll
        for (int j=0;j<4;++j){
            int col = bn*128 + wc*64 + j*16 + (lane&15);
            #pragma unroll
            for (int e=0;e<4;++e){
                int row = bm*128 + wr*64 + i*16 + (lane>>4)*4 + e;
                float v = acc[i][j][e];
                if (Cb0){
                    if (col < split) Cb0[(long)row*split + col] = f2b(v);
                    else             Cb1[(long)row*split + (col-split)] = f2b(v);
                } else {
                    Cf[(long)row*N + col] = v;
                }
            }
        }
    }
}

// ---------------- depthwise conv, 8 rows/block ----------------
__global__ __launch_bounds__(256) void conv2_k(
    const u16* __restrict__ xb, const float* __restrict__ cw, const float* __restrict__ cb,
    u16* __restrict__ ub)
{
    int rb = blockIdx.x;
    int t0g = rb*8;
    int b = t0g >> 12, t0 = t0g & 4095;
    int d0 = threadIdx.x * 8;
    float w[4][8];
    #pragma unroll
    for (int e=0;e<8;++e){
        f32x4 wv = *(const f32x4*)(cw + (d0+e)*4);
        w[0][e]=wv[0]; w[1][e]=wv[1]; w[2][e]=wv[2]; w[3][e]=wv[3];
    }
    float bias[8];
    #pragma unroll
    for (int e=0;e<8;++e) bias[e] = cb[d0+e];

    bf16x8 xr[11];
    #pragma unroll
    for (int r=0;r<11;++r){
        int tr = t0 - 3 + r;
        bf16x8 v = 0;
        if (tr >= 0 && r < 8+3) v = *(const bf16x8*)(xb + ((long)(b*4096 + tr))*2048 + d0);
        xr[r] = v;
    }
    #pragma unroll
    for (int r=0;r<8;++r){
        bf16x8 o;
        #pragma unroll
        for (int e=0;e<8;++e){
            float acc = bias[e];
            #pragma unroll
            for (int j=0;j<4;++j) acc += b2f((u16)xr[r+j][e]) * w[j][e];
            o[e] = (short)f2b(silu_f(acc));
        }
        *(bf16x8*)(ub + ((long)(t0g + r))*2048 + d0) = o;
    }
}

// ---------------- dt softplus ----------------
__global__ __launch_bounds__(256) void dtv_k(const float* __restrict__ xp, const float* __restrict__ dtb, float* __restrict__ dtv){
    int i = blockIdx.x*256 + threadIdx.x;
    int row = i >> 4, h = i & 15;
    float x = xp[(long)row*DTN + h] + dtb[h];
    float sp = (x > 15.f) ? x : __logf(1.f + __expf(x));
    dtv[i] = sp;
}

// ---------------- scan phase A: split-n, f32 A2, unroll-2 t-loop ----------------
__global__ __launch_bounds__(256) void scanA11_k(
    const u16* __restrict__ ub, const float* __restrict__ dtv,
    const float* __restrict__ xpf, const float* __restrict__ A2f,
    u16* __restrict__ states, float* __restrict__ dtsum)
{
    __shared__ u16 uL[CHUNK][256];        // 32 KB
    int blk = blockIdx.x;                 // ((b*NCHUNK+c)*16 + g*2 + nh)
    int g2 = blk & 15; int g = g2 >> 1; int nh = g2 & 1;
    int bc = blk >> 4; int c = bc & (NCHUNK-1); int b = bc >> 6;
    int tid = threadIdx.x;
    int d = g*256 + tid;
    int n0 = nh*32;
    int base = b*SEQLEN + c*CHUNK;
    int h = __builtin_amdgcn_readfirstlane(g*2 + ((tid>>7)&1));

    for (int i = tid; i < CHUNK*32; i += 256){
        int t = i >> 5, seg = i & 31;
        *(bf16x8*)&uL[t][seg*8] = *(const bf16x8*)(ub + (long)(base+t)*2048 + g*256 + seg*8);
    }
    __syncthreads();

    float A2[32];
    #pragma unroll
    for (int j=0;j<32;++j) A2[j] = A2f[(long)(n0+j)*2048 + d];

    float s[32];
    #pragma unroll
    for (int n=0;n<32;++n) s[n] = 0.f;
    float dts = 0.f;
    #pragma unroll 2
    for (int t=0;t<CHUNK;++t){
        int row = __builtin_amdgcn_readfirstlane(base + t);
        const float* xr = xpf + (long)row*DTN + 16 + n0;
        float dtc = dtv[row*16 + h];
        float uu = b2f(uL[t][tid]);
        float dtu = dtc*uu;
        dts += dtc;
        #pragma unroll
        for (int n=0;n<32;++n){
            float e = fexp2(dtc*A2[n]);
            s[n] = fmaf(s[n], e, dtu*xr[n]);
        }
    }
    long sb = ((long)((b*NCHUNK + c)*64) + n0)*2048 + d;
    #pragma unroll
    for (int n=0;n<32;++n) states[sb + (long)n*2048] = f2b(s[n]);
    if (nh == 0) dtsum[(long)(b*NCHUNK+c)*2048 + d] = dts;
}

// ---------------- scan phase B: prefix-combine over chunks (in-place, bf16 states) ----------------
__global__ __launch_bounds__(256) void scanB8_k(
    u16* __restrict__ states, const float* __restrict__ dtsum, const u32* __restrict__ A2v)
{
    int idx = blockIdx.x*256 + threadIdx.x;
    int b = idx >> 17;
    int r = idx & 131071;
    int n = r >> 11; int d = r & 2047;
    u32 pk = A2v[((long)(n>>3)*2048 + d)*4 + ((n>>1)&3)];
    float A2 = (n&1) ? __builtin_bit_cast(float, pk & 0xFFFF0000u)
                     : __builtin_bit_cast(float, pk<<16);
    float carry = 0.f;
    for (int c=0;c<NCHUNK;++c){
        long off = ((long)((b*NCHUNK+c)*64 + n))*2048 + d;
        float loc = b2f(states[off]);
        states[off] = f2b(carry);
        float ds = dtsum[(long)(b*NCHUNK+c)*2048 + d];
        carry = carry*fexp2(A2*ds) + loc;
    }
}

// ---------------- scan phase C: merged halves (1024 blocks), bf16 partials ----------------
__global__ __launch_bounds__(256) void scanC12_k(
    const u16* __restrict__ ub, const float* __restrict__ dtv,
    const float* __restrict__ xpf, const float* __restrict__ A2f,
    const u16* __restrict__ states,
    u16* __restrict__ Yp0, u16* __restrict__ Yp1)
{
    __shared__ u16 uL[CHUNK][256];        // 32 KB
    int blk = blockIdx.x;                 // ((b*NCHUNK+c)*16 + g*2 + nh)
    int g2 = blk & 15; int g = g2 >> 1; int nh = g2 & 1;
    int bc = blk >> 4; int c = bc & (NCHUNK-1); int b = bc >> 6;
    int tid = threadIdx.x;
    int d = g*256 + tid;
    int n0 = nh*32;
    int base = b*SEQLEN + c*CHUNK;
    int h = __builtin_amdgcn_readfirstlane(g*2 + ((tid>>7)&1));
    u16* Yp = nh ? Yp1 : Yp0;

    for (int i = tid; i < CHUNK*32; i += 256){
        int t = i >> 5, seg = i & 31;
        *(bf16x8*)&uL[t][seg*8] = *(const bf16x8*)(ub + (long)(base+t)*2048 + g*256 + seg*8);
    }
    __syncthreads();

    float A2[32];
    #pragma unroll
    for (int j=0;j<32;++j) A2[j] = A2f[(long)(n0+j)*2048 + d];

    float s[32];
    long sb = ((long)((b*NCHUNK + c)*64) + n0)*2048 + d;
    #pragma unroll
    for (int n=0;n<32;++n) s[n] = b2f(states[sb + (long)n*2048]);
    for (int t=0;t<CHUNK;++t){
        int row = __builtin_amdgcn_readfirstlane(base + t);
        const float* xr = xpf + (long)row*DTN + 16 + n0;
        const float* xc = xr + 64;
        float dtc = dtv[row*16 + h];
        float uu = b2f(uL[t][tid]);
        float dtu = dtc*uu;
        float y0=0.f, y1=0.f;
        #pragma unroll
        for (int n=0;n<32;n+=2){
            float e0 = fexp2(dtc*A2[n]);
            float e1 = fexp2(dtc*A2[n+1]);
            s[n]   = fmaf(s[n],   e0, dtu*xr[n]);
            s[n+1] = fmaf(s[n+1], e1, dtu*xr[n+1]);
            y0 = fmaf(s[n],   xc[n],   y0);
            y1 = fmaf(s[n+1], xc[n+1], y1);
        }
        Yp[(long)row*2048 + d] = f2b(y0 + y1);
    }
}

// ---------------- combine partials + D-term -> Y (bf16) ----------------
__global__ __launch_bounds__(256) void combine_k(
    u16* __restrict__ Y, const u16* __restrict__ Yp1,
    const u16* __restrict__ ub, const float* __restrict__ Dv)
{
    long i8 = ((long)blockIdx.x*256 + threadIdx.x)*8;   // over NROWS*2048
    int d0 = (int)(i8 & 2047);
    bf16x8 p0 = *(const bf16x8*)(Y   + i8);
    bf16x8 p1 = *(const bf16x8*)(Yp1 + i8);
    bf16x8 uv = *(const bf16x8*)(ub  + i8);
    f32x4 D0 = *(const f32x4*)(Dv + d0);
    f32x4 D1 = *(const f32x4*)(Dv + d0 + 4);
    bf16x8 o;
    #pragma unroll
    for (int e=0;e<8;++e){
        float Dd = (e<4) ? D0[e] : D1[e-4];
        float y = b2f((u16)p0[e]) + b2f((u16)p1[e]) + b2f((u16)uv[e])*Dd;
        o[e] = (short)f2b(y);
    }
    *(bf16x8*)(Y + i8) = o;
}

// ---------------- gate (y * silu(z)) + LayerNorm, in-place over Y (bf16) ----------------
__global__ __launch_bounds__(256) void gatenorm_k(
    u16* __restrict__ Y, const u16* __restrict__ zb,
    const float* __restrict__ nw, const float* __restrict__ nb)
{
    int row = blockIdx.x;
    int tid = threadIdx.x;
    int d0 = tid*8;
    bf16x8 zv = *(const bf16x8*)(zb + (long)row*2048 + d0);
    bf16x8 yv = *(const bf16x8*)(Y + (long)row*2048 + d0);
    float gv[8];
    #pragma unroll
    for (int e=0;e<8;++e){
        float y = b2f((u16)yv[e]);
        float z = b2f((u16)zv[e]);
        gv[e] = y * silu_f(z);
    }
    float s1=0.f, s2=0.f;
    #pragma unroll
    for (int e=0;e<8;++e){ s1 += gv[e]; s2 += gv[e]*gv[e]; }
    #pragma unroll
    for (int o=32;o>0;o>>=1){ s1 += __shfl_xor(s1,o,64); s2 += __shfl_xor(s2,o,64); }
    __shared__ float red[2][4];
    int wave = tid>>6, lane = tid&63;
    if (lane==0){ red[0][wave]=s1; red[1][wave]=s2; }
    __syncthreads();
    s1 = red[0][0]+red[0][1]+red[0][2]+red[0][3];
    s2 = red[1][0]+red[1][1]+red[1][2]+red[1][3];
    float mu = s1 * (1.f/2048.f);
    float var = s2 * (1.f/2048.f) - mu*mu;
    float rs = rsqrtf(var + 1e-5f);
    bf16x8 o;
    #pragma unroll
    for (int e=0;e<8;++e){
        float v = (gv[e]-mu)*rs*nw[d0+e] + nb[d0+e];
        o[e] = (short)f2b(v);
    }
    *(bf16x8*)(Y + (long)row*2048 + d0) = o;
}

extern "C" void kernel_launch(void* const* d_in, const int* in_sizes, int n_in,
                              void* d_out, int out_size, void* d_ws, size_t ws_size,
                              hipStream_t stream)
{
    const float* hidden = (const float*)d_in[0];
    const float* w_in   = (const float*)d_in[1];
    const float* conv_w = (const float*)d_in[2];
    const float* conv_b = (const float*)d_in[3];
    const float* w_dt   = (const float*)d_in[4];
    const float* b_dt   = (const float*)d_in[5];
    const float* dt_bias= (const float*)d_in[6];
    const float* A_log  = (const float*)d_in[7];
    const float* Dv     = (const float*)d_in[8];
    const float* norm_w = (const float*)d_in[9];
    const float* norm_b = (const float*)d_in[10];
    const float* w_out  = (const float*)d_in[11];

    char* ws = (char*)d_ws;

    const size_t SZ_hb   = (size_t)NROWS*DMODEL*2;
    const size_t SZ_wib  = (size_t)2*DINNER*DMODEL*2;
    const size_t SZ_regA = SZ_hb + SZ_wib;
    const size_t SZ_big  = (size_t)NROWS*DINNER*2;
    const size_t SZ_wdtb = (size_t)DTN*DINNER*2;
    const size_t SZ_xpf  = (size_t)NROWS*DTN*4;
    const size_t SZ_dtv  = (size_t)NROWS*16*4;
    const size_t SZ_A2   = (size_t)DINNER*32*4;
    const size_t SZ_A2f  = (size_t)DINNER*DSTATE*4;
    const size_t SZ_states = (size_t)BATCH*NCHUNK*DSTATE*DINNER*2;
    const size_t SZ_dtsum  = (size_t)BATCH*NCHUNK*DINNER*4;

    size_t off = 0;
    auto take = [&](size_t bytes)->char*{ char* p = ws + off; off += (bytes + 255) & ~(size_t)255; return p; };

    char* regA = take(SZ_regA);
    u16*  hb   = (u16*)regA;
    u16*  wib  = (u16*)(regA + SZ_hb);
    u16*  wdtb = (u16*)regA;                                  // after in_proj
    u16*  wob  = (u16*)(regA + ((SZ_wdtb + 255) & ~(size_t)255));
    u16*  xb   = (u16*)take(SZ_big);                          // x; Y(partial0) aliases after conv
    u16*  zb   = (u16*)take(SZ_big);
    u16*  ub   = (u16*)take(SZ_big);
    u16*  Yp1  = (u16*)take(SZ_big);                          // partial1
    float* xpf = (float*)take(SZ_xpf);
    float* dtv = (float*)take(SZ_dtv);
    u32*  A2v  = (u32*)take(SZ_A2);
    float* A2f = (float*)take(SZ_A2f);
    u16*  states = (u16*)take(SZ_states);
    float* dtsum  = (float*)take(SZ_dtsum);
    u16*  Y    = xb;
    if (off > ws_size) return;

    { int n = NROWS*DMODEL;       cast_k<<<dim3((n/8+255)/256), dim3(256), 0, stream>>>(hidden, hb, n); }
    { int n = 2*DINNER*DMODEL;    cast_k<<<dim3((n/8+255)/256), dim3(256), 0, stream>>>(w_in, wib, n); }
    a2pack_k<<<dim3(DINNER*8/256), dim3(256), 0, stream>>>(A_log, A2v);
    a2packf_k<<<dim3(DINNER*DSTATE/256), dim3(256), 0, stream>>>(A_log, A2f);

    gemm128_k<<<dim3((2*DINNER)/128, NROWS/128), dim3(256), 0, stream>>>(hb, wib, nullptr, xb, zb, DINNER, NROWS, 2*DINNER, DMODEL);

    { int n = DTN*DINNER;         cast_k<<<dim3((n/8+255)/256), dim3(256), 0, stream>>>(w_dt, wdtb, n); }
    { int n = DMODEL*DINNER;      cast_k<<<dim3((n/8+255)/256), dim3(256), 0, stream>>>(w_out, wob, n); }

    conv2_k<<<dim3(NROWS/8), dim3(256), 0, stream>>>(xb, conv_w, conv_b, ub);
    xpinit_k<<<dim3((NROWS*DTN + 255)/256), dim3(256), 0, stream>>>(xpf, b_dt);
    gemmsk_k<<<dim3((DTN+63)/64, NROWS/64, 4), dim3(256), 0, stream>>>(ub, wdtb, xpf, NROWS, DTN, DINNER, DINNER/4);
    dtv_k<<<dim3(NROWS*16/256), dim3(256), 0, stream>>>(xpf, dt_bias, dtv);

    scanA11_k<<<dim3(BATCH*NCHUNK*16), dim3(256), 0, stream>>>(ub, dtv, xpf, A2f, states, dtsum);
    scanB8_k<<<dim3(BATCH*DSTATE*DINNER/256), dim3(256), 0, stream>>>(states, dtsum, A2v);
    scanC12_k<<<dim3(BATCH*NCHUNK*16), dim3(256), 0, stream>>>(ub, dtv, xpf, A2f, states, Y, Yp1);
    combine_k<<<dim3(NROWS*DINNER/8/256), dim3(256), 0, stream>>>(Y, Yp1, ub, Dv);

    gatenorm_k<<<dim3(NROWS), dim3(256), 0, stream>>>(Y, zb, norm_w, norm_b);
    gemm128_k<<<dim3(DMODEL/128, NROWS/128), dim3(256), 0, stream>>>(Y, wob, (float*)d_out, nullptr, nullptr, 0, NROWS, DMODEL, DINNER);
}

// Round 20
// 584.863 us; speedup vs baseline: 1.1129x; 1.0231x over previous
//
#include <hip/hip_runtime.h>
#include <hip/hip_bf16.h>

#define DMODEL 1024
#define DINNER 2048
#define DSTATE 64
#define BATCH 2
#define SEQLEN 4096
#define NROWS (BATCH*SEQLEN)          // 8192
#define DTN 144                        // NHEADS + 2*DSTATE
#define CHUNK 64
#define NCHUNK (SEQLEN/CHUNK)          // 64

typedef unsigned short u16;
typedef unsigned int u32;
typedef __attribute__((ext_vector_type(8))) short bf16x8;
typedef __attribute__((ext_vector_type(4))) float f32x4;
typedef __attribute__((ext_vector_type(4))) u32 u32x4;

__device__ __forceinline__ float b2f(u16 u){ u32 i = ((u32)u)<<16; return __builtin_bit_cast(float, i); }
__device__ __forceinline__ u16 f2b(float f){ u32 i = __builtin_bit_cast(u32, f); u32 r = (i + 0x7FFFu + ((i>>16)&1u))>>16; return (u16)r; }
__device__ __forceinline__ float silu_f(float x){ return x / (1.f + __expf(-x)); }
__device__ __forceinline__ float fexp2(float x){ float r; asm("v_exp_f32 %0, %1" : "=v"(r) : "v"(x)); return r; }

__device__ __forceinline__ void gload16(const u16* g, u16* l){
    __builtin_amdgcn_global_load_lds((const __attribute__((address_space(1))) void*)g,
                                     (__attribute__((address_space(3))) void*)l, 16, 0, 0);
}

// ---------------- cast fp32 -> bf16 ----------------
__global__ __launch_bounds__(256) void cast_k(const float* __restrict__ in, u16* __restrict__ out, int n){
    int i = (blockIdx.x*256 + threadIdx.x)*8;
    if (i + 8 > n) return;
    f32x4 a = *(const f32x4*)(in + i);
    f32x4 b = *(const f32x4*)(in + i + 4);
    bf16x8 o;
    o[0]=(short)f2b(a[0]); o[1]=(short)f2b(a[1]); o[2]=(short)f2b(a[2]); o[3]=(short)f2b(a[3]);
    o[4]=(short)f2b(b[0]); o[5]=(short)f2b(b[1]); o[6]=(short)f2b(b[2]); o[7]=(short)f2b(b[3]);
    *(bf16x8*)(out + i) = o;
}

// ---------------- A2 pack (bf16 pairs, for scanB) ----------------
__global__ __launch_bounds__(256) void a2pack_k(const float* __restrict__ Alog, u32* __restrict__ A2v){
    int i = blockIdx.x*256 + threadIdx.x;     // < 16384
    int d = i & 2047, k4 = i >> 11;
    u32x4 o;
    #pragma unroll
    for (int j=0;j<4;++j){
        int n0 = (k4*4+j)*2;
        float a0 = -__expf(Alog[(long)d*64 + n0    ]) * 1.44269504f;
        float a1 = -__expf(Alog[(long)d*64 + n0 + 1]) * 1.44269504f;
        o[j] = (u32)f2b(a0) | ((u32)f2b(a1)<<16);
    }
    *(u32x4*)(A2v + ((long)k4*2048 + d)*4) = o;
}

// ---------------- A2 expanded f32, transposed: A2f[n][d] ----------------
__global__ __launch_bounds__(256) void a2packf_k(const float* __restrict__ Alog, float* __restrict__ A2f){
    int i = blockIdx.x*256 + threadIdx.x;     // < 131072
    int n = i >> 11, d = i & 2047;
    A2f[i] = -__expf(Alog[(long)d*64 + n]) * 1.44269504f;
}

// ---------------- xpf init: broadcast dt_proj bias into every row ----------------
__global__ __launch_bounds__(256) void xpinit_k(float* __restrict__ xpf, const float* __restrict__ bias){
    int i = blockIdx.x*256 + threadIdx.x;        // < NROWS*DTN
    if (i >= NROWS*DTN) return;
    xpf[i] = bias[i % DTN];
}

// ---------------- split-K skinny GEMM (64x64 tile, blockIdx.z = K-slice), atomicAdd epilogue ----------------
__global__ __launch_bounds__(256) void gemmsk_k(
    const u16* __restrict__ A, const u16* __restrict__ B,
    float* __restrict__ Cf, int M, int N, int K, int klen)
{
    __shared__ u16 lA[64][72];
    __shared__ u16 lB[64][72];
    int tid = threadIdx.x;
    int bm = blockIdx.y, bn = blockIdx.x;
    int kbase = blockIdx.z * klen;
    int wave = tid>>6, lane = tid&63;
    int wr = wave>>1, wc = wave&1;
    f32x4 acc[2][2];
    #pragma unroll
    for (int r=0;r<2;++r)
    #pragma unroll
    for (int c=0;c<2;++c) acc[r][c] = 0.f;

    int lr = tid>>3;
    int lc = (tid&7)*8;
    long arow0 = (long)(bm*64 + lr)*K;
    long arow1 = (long)(bm*64 + lr + 32)*K;
    int brow0 = bn*64 + lr, brow1 = brow0 + 32;

    for (int k0 = kbase; k0 < kbase + klen; k0 += 64){
        __syncthreads();
        *(bf16x8*)&lA[lr][lc]    = *(const bf16x8*)(A + arow0 + k0 + lc);
        *(bf16x8*)&lA[lr+32][lc] = *(const bf16x8*)(A + arow1 + k0 + lc);
        bf16x8 b0 = 0, b1 = 0;
        if (brow0 < N) b0 = *(const bf16x8*)(B + (long)brow0*K + k0 + lc);
        if (brow1 < N) b1 = *(const bf16x8*)(B + (long)brow1*K + k0 + lc);
        *(bf16x8*)&lB[lr][lc]    = b0;
        *(bf16x8*)&lB[lr+32][lc] = b1;
        __syncthreads();
        int rA0 = wr*32 + (lane&15);
        int cB0 = wc*32 + (lane&15);
        int kl  = (lane>>4)*8;
        #pragma unroll
        for (int kk = 0; kk < 64; kk += 32){
            bf16x8 a0 = *(const bf16x8*)&lA[rA0   ][kk+kl];
            bf16x8 a1 = *(const bf16x8*)&lA[rA0+16][kk+kl];
            bf16x8 v0 = *(const bf16x8*)&lB[cB0   ][kk+kl];
            bf16x8 v1 = *(const bf16x8*)&lB[cB0+16][kk+kl];
            acc[0][0] = __builtin_amdgcn_mfma_f32_16x16x32_bf16(a0, v0, acc[0][0], 0,0,0);
            acc[0][1] = __builtin_amdgcn_mfma_f32_16x16x32_bf16(a0, v1, acc[0][1], 0,0,0);
            acc[1][0] = __builtin_amdgcn_mfma_f32_16x16x32_bf16(a1, v0, acc[1][0], 0,0,0);
            acc[1][1] = __builtin_amdgcn_mfma_f32_16x16x32_bf16(a1, v1, acc[1][1], 0,0,0);
        }
    }
    #pragma unroll
    for (int r=0;r<2;++r){
        #pragma unroll
        for (int c=0;c<2;++c){
            int col = bn*64 + wc*32 + c*16 + (lane&15);
            if (col >= N) continue;
            #pragma unroll
            for (int e=0;e<4;++e){
                int row = bm*64 + wr*32 + r*16 + (lane>>4)*4 + e;
                atomicAdd(&Cf[(long)row*N + col], acc[r][c][e]);
            }
        }
    }
}

// ---------------- m97-style 128x128 GEMM + XCD-aware block swizzle ----------------
__global__ __launch_bounds__(256) void gemm128_k(
    const u16* __restrict__ A, const u16* __restrict__ B,
    float* __restrict__ Cf, u16* __restrict__ Cb0, u16* __restrict__ Cb1, int split,
    int M, int N, int K)
{
    __shared__ u16 lA[128*64];
    __shared__ u16 lB[128*64];
    int tid = threadIdx.x, wave = tid>>6, lane = tid&63;
    int nwgx = gridDim.x;
    int flat = blockIdx.y*nwgx + blockIdx.x;
    int q = (nwgx*gridDim.y) >> 3;
    int nf = (flat & 7)*q + (flat >> 3);
    int bn = nf % nwgx, bm = nf / nwgx;
    int wr = wave>>1, wc = wave&1;
    f32x4 acc[4][4];
    #pragma unroll
    for (int i=0;i<4;++i)
    #pragma unroll
    for (int j=0;j<4;++j) acc[i][j] = 0.f;

    int srow = lane>>3;
    int scol = (lane&7)*8;
    const u16* Abase = A + (long)(bm*128)*K;
    const u16* Bbase = B + (long)(bn*128)*K;

    for (int k0 = 0; k0 < K; k0 += 64){
        __syncthreads();
        #pragma unroll
        for (int i=0;i<4;++i){
            int qq = i*4 + wave;
            int r = qq*8 + srow;
            gload16(Abase + (long)r*K + k0 + scol, &lA[qq*512]);
            gload16(Bbase + (long)r*K + k0 + scol, &lB[qq*512]);
        }
        __syncthreads();
        #pragma unroll
        for (int kk=0; kk<64; kk+=32){
            int kb = kk + ((lane>>4)<<3);
            bf16x8 af[4], bfr[4];
            #pragma unroll
            for (int i=0;i<4;++i) af[i]  = *(const bf16x8*)&lA[(wr*64 + i*16 + (lane&15))*64 + kb];
            #pragma unroll
            for (int j=0;j<4;++j) bfr[j] = *(const bf16x8*)&lB[(wc*64 + j*16 + (lane&15))*64 + kb];
            #pragma unroll
            for (int i=0;i<4;++i)
            #pragma unroll
            for (int j=0;j<4;++j)
                acc[i][j] = __builtin_amdgcn_mfma_f32_16x16x32_bf16(af[i], bfr[j], acc[i][j], 0,0,0);
        }
    }
    #pragma unroll
    for (int i=0;i<4;++i){
        #pragma unroll
        for (int j=0;j<4;++j){
            int col = bn*128 + wc*64 + j*16 + (lane&15);
            #pragma unroll
            for (int e=0;e<4;++e){
                int row = bm*128 + wr*64 + i*16 + (lane>>4)*4 + e;
                float v = acc[i][j][e];
                if (Cb0){
                    if (col < split) Cb0[(long)row*split + col] = f2b(v);
                    else             Cb1[(long)row*split + (col-split)] = f2b(v);
                } else {
                    Cf[(long)row*N + col] = v;
                }
            }
        }
    }
}

// ---------------- depthwise conv, 8 rows/block ----------------
__global__ __launch_bounds__(256) void conv2_k(
    const u16* __restrict__ xb, const float* __restrict__ cw, const float* __restrict__ cb,
    u16* __restrict__ ub)
{
    int rb = blockIdx.x;
    int t0g = rb*8;
    int b = t0g >> 12, t0 = t0g & 4095;
    int d0 = threadIdx.x * 8;
    float w[4][8];
    #pragma unroll
    for (int e=0;e<8;++e){
        f32x4 wv = *(const f32x4*)(cw + (d0+e)*4);
        w[0][e]=wv[0]; w[1][e]=wv[1]; w[2][e]=wv[2]; w[3][e]=wv[3];
    }
    float bias[8];
    #pragma unroll
    for (int e=0;e<8;++e) bias[e] = cb[d0+e];

    bf16x8 xr[11];
    #pragma unroll
    for (int r=0;r<11;++r){
        int tr = t0 - 3 + r;
        bf16x8 v = 0;
        if (tr >= 0 && r < 8+3) v = *(const bf16x8*)(xb + ((long)(b*4096 + tr))*2048 + d0);
        xr[r] = v;
    }
    #pragma unroll
    for (int r=0;r<8;++r){
        bf16x8 o;
        #pragma unroll
        for (int e=0;e<8;++e){
            float acc = bias[e];
            #pragma unroll
            for (int j=0;j<4;++j) acc += b2f((u16)xr[r+j][e]) * w[j][e];
            o[e] = (short)f2b(silu_f(acc));
        }
        *(bf16x8*)(ub + ((long)(t0g + r))*2048 + d0) = o;
    }
}

// ---------------- dt softplus ----------------
__global__ __launch_bounds__(256) void dtv_k(const float* __restrict__ xp, const float* __restrict__ dtb, float* __restrict__ dtv){
    int i = blockIdx.x*256 + threadIdx.x;
    int row = i >> 4, h = i & 15;
    float x = xp[(long)row*DTN + h] + dtb[h];
    float sp = (x > 15.f) ? x : __logf(1.f + __expf(x));
    dtv[i] = sp;
}

// ---------------- scan phase A: split-n, f32 A2, unroll-2 t-loop ----------------
__global__ __launch_bounds__(256) void scanA11_k(
    const u16* __restrict__ ub, const float* __restrict__ dtv,
    const float* __restrict__ xpf, const float* __restrict__ A2f,
    u16* __restrict__ states, float* __restrict__ dtsum)
{
    __shared__ u16 uL[CHUNK][256];        // 32 KB
    int blk = blockIdx.x;                 // ((b*NCHUNK+c)*16 + g*2 + nh)
    int g2 = blk & 15; int g = g2 >> 1; int nh = g2 & 1;
    int bc = blk >> 4; int c = bc & (NCHUNK-1); int b = bc >> 6;
    int tid = threadIdx.x;
    int d = g*256 + tid;
    int n0 = nh*32;
    int base = b*SEQLEN + c*CHUNK;
    int h = __builtin_amdgcn_readfirstlane(g*2 + ((tid>>7)&1));

    for (int i = tid; i < CHUNK*32; i += 256){
        int t = i >> 5, seg = i & 31;
        *(bf16x8*)&uL[t][seg*8] = *(const bf16x8*)(ub + (long)(base+t)*2048 + g*256 + seg*8);
    }
    __syncthreads();

    float A2[32];
    #pragma unroll
    for (int j=0;j<32;++j) A2[j] = A2f[(long)(n0+j)*2048 + d];

    float s[32];
    #pragma unroll
    for (int n=0;n<32;++n) s[n] = 0.f;
    float dts = 0.f;
    #pragma unroll 2
    for (int t=0;t<CHUNK;++t){
        int row = __builtin_amdgcn_readfirstlane(base + t);
        const float* xr = xpf + (long)row*DTN + 16 + n0;
        float dtc = dtv[row*16 + h];
        float uu = b2f(uL[t][tid]);
        float dtu = dtc*uu;
        dts += dtc;
        #pragma unroll
        for (int n=0;n<32;++n){
            float e = fexp2(dtc*A2[n]);
            s[n] = fmaf(s[n], e, dtu*xr[n]);
        }
    }
    long sb = ((long)((b*NCHUNK + c)*64) + n0)*2048 + d;
    #pragma unroll
    for (int n=0;n<32;++n) states[sb + (long)n*2048] = f2b(s[n]);
    if (nh == 0) dtsum[(long)(b*NCHUNK+c)*2048 + d] = dts;
}

// ---------------- scan phase B: prefix-combine over chunks (in-place, bf16 states) ----------------
__global__ __launch_bounds__(256) void scanB8_k(
    u16* __restrict__ states, const float* __restrict__ dtsum, const u32* __restrict__ A2v)
{
    int idx = blockIdx.x*256 + threadIdx.x;
    int b = idx >> 17;
    int r = idx & 131071;
    int n = r >> 11; int d = r & 2047;
    u32 pk = A2v[((long)(n>>3)*2048 + d)*4 + ((n>>1)&3)];
    float A2 = (n&1) ? __builtin_bit_cast(float, pk & 0xFFFF0000u)
                     : __builtin_bit_cast(float, pk<<16);
    float carry = 0.f;
    for (int c=0;c<NCHUNK;++c){
        long off = ((long)((b*NCHUNK+c)*64 + n))*2048 + d;
        float loc = b2f(states[off]);
        states[off] = f2b(carry);
        float ds = dtsum[(long)(b*NCHUNK+c)*2048 + d];
        carry = carry*fexp2(A2*ds) + loc;
    }
}

// ---------------- scan phase C: merged halves (1024 blocks), bf16 partials ----------------
__global__ __launch_bounds__(256) void scanC12_k(
    const u16* __restrict__ ub, const float* __restrict__ dtv,
    const float* __restrict__ xpf, const float* __restrict__ A2f,
    const u16* __restrict__ states,
    u16* __restrict__ Yp0, u16* __restrict__ Yp1)
{
    __shared__ u16 uL[CHUNK][256];        // 32 KB
    int blk = blockIdx.x;                 // ((b*NCHUNK+c)*16 + g*2 + nh)
    int g2 = blk & 15; int g = g2 >> 1; int nh = g2 & 1;
    int bc = blk >> 4; int c = bc & (NCHUNK-1); int b = bc >> 6;
    int tid = threadIdx.x;
    int d = g*256 + tid;
    int n0 = nh*32;
    int base = b*SEQLEN + c*CHUNK;
    int h = __builtin_amdgcn_readfirstlane(g*2 + ((tid>>7)&1));
    u16* Yp = nh ? Yp1 : Yp0;

    for (int i = tid; i < CHUNK*32; i += 256){
        int t = i >> 5, seg = i & 31;
        *(bf16x8*)&uL[t][seg*8] = *(const bf16x8*)(ub + (long)(base+t)*2048 + g*256 + seg*8);
    }
    __syncthreads();

    float A2[32];
    #pragma unroll
    for (int j=0;j<32;++j) A2[j] = A2f[(long)(n0+j)*2048 + d];

    float s[32];
    long sb = ((long)((b*NCHUNK + c)*64) + n0)*2048 + d;
    #pragma unroll
    for (int n=0;n<32;++n) s[n] = b2f(states[sb + (long)n*2048]);
    for (int t=0;t<CHUNK;++t){
        int row = __builtin_amdgcn_readfirstlane(base + t);
        const float* xr = xpf + (long)row*DTN + 16 + n0;
        const float* xc = xr + 64;
        float dtc = dtv[row*16 + h];
        float uu = b2f(uL[t][tid]);
        float dtu = dtc*uu;
        float y0=0.f, y1=0.f;
        #pragma unroll
        for (int n=0;n<32;n+=2){
            float e0 = fexp2(dtc*A2[n]);
            float e1 = fexp2(dtc*A2[n+1]);
            s[n]   = fmaf(s[n],   e0, dtu*xr[n]);
            s[n+1] = fmaf(s[n+1], e1, dtu*xr[n+1]);
            y0 = fmaf(s[n],   xc[n],   y0);
            y1 = fmaf(s[n+1], xc[n+1], y1);
        }
        Yp[(long)row*2048 + d] = f2b(y0 + y1);
    }
}

// ---------------- fused: combine partials + D-term + gate(silu) + LayerNorm -> Y (bf16) ----------------
__global__ __launch_bounds__(256) void gatenorm2_k(
    u16* __restrict__ Y, const u16* __restrict__ Yp1,
    const u16* __restrict__ ub, const float* __restrict__ Dv,
    const u16* __restrict__ zb,
    const float* __restrict__ nw, const float* __restrict__ nb)
{
    int row = blockIdx.x;
    int tid = threadIdx.x;
    int d0 = tid*8;
    long base = (long)row*2048 + d0;
    bf16x8 p0 = *(const bf16x8*)(Y   + base);
    bf16x8 p1 = *(const bf16x8*)(Yp1 + base);
    bf16x8 uv = *(const bf16x8*)(ub  + base);
    bf16x8 zv = *(const bf16x8*)(zb  + base);
    f32x4 D0 = *(const f32x4*)(Dv + d0);
    f32x4 D1 = *(const f32x4*)(Dv + d0 + 4);
    float gv[8];
    #pragma unroll
    for (int e=0;e<8;++e){
        float Dd = (e<4) ? D0[e] : D1[e-4];
        float y = b2f((u16)p0[e]) + b2f((u16)p1[e]) + b2f((u16)uv[e])*Dd;
        float z = b2f((u16)zv[e]);
        gv[e] = y * silu_f(z);
    }
    float s1=0.f, s2=0.f;
    #pragma unroll
    for (int e=0;e<8;++e){ s1 += gv[e]; s2 += gv[e]*gv[e]; }
    #pragma unroll
    for (int o=32;o>0;o>>=1){ s1 += __shfl_xor(s1,o,64); s2 += __shfl_xor(s2,o,64); }
    __shared__ float red[2][4];
    int wave = tid>>6, lane = tid&63;
    if (lane==0){ red[0][wave]=s1; red[1][wave]=s2; }
    __syncthreads();
    s1 = red[0][0]+red[0][1]+red[0][2]+red[0][3];
    s2 = red[1][0]+red[1][1]+red[1][2]+red[1][3];
    float mu = s1 * (1.f/2048.f);
    float var = s2 * (1.f/2048.f) - mu*mu;
    float rs = rsqrtf(var + 1e-5f);
    bf16x8 o;
    #pragma unroll
    for (int e=0;e<8;++e){
        float v = (gv[e]-mu)*rs*nw[d0+e] + nb[d0+e];
        o[e] = (short)f2b(v);
    }
    *(bf16x8*)(Y + base) = o;
}

extern "C" void kernel_launch(void* const* d_in, const int* in_sizes, int n_in,
                              void* d_out, int out_size, void* d_ws, size_t ws_size,
                              hipStream_t stream)
{
    const float* hidden = (const float*)d_in[0];
    const float* w_in   = (const float*)d_in[1];
    const float* conv_w = (const float*)d_in[2];
    const float* conv_b = (const float*)d_in[3];
    const float* w_dt   = (const float*)d_in[4];
    const float* b_dt   = (const float*)d_in[5];
    const float* dt_bias= (const float*)d_in[6];
    const float* A_log  = (const float*)d_in[7];
    const float* Dv     = (const float*)d_in[8];
    const float* norm_w = (const float*)d_in[9];
    const float* norm_b = (const float*)d_in[10];
    const float* w_out  = (const float*)d_in[11];

    char* ws = (char*)d_ws;

    const size_t SZ_hb   = (size_t)NROWS*DMODEL*2;
    const size_t SZ_wib  = (size_t)2*DINNER*DMODEL*2;
    const size_t SZ_regA = SZ_hb + SZ_wib;
    const size_t SZ_big  = (size_t)NROWS*DINNER*2;
    const size_t SZ_wdtb = (size_t)DTN*DINNER*2;
    const size_t SZ_xpf  = (size_t)NROWS*DTN*4;
    const size_t SZ_dtv  = (size_t)NROWS*16*4;
    const size_t SZ_A2   = (size_t)DINNER*32*4;
    const size_t SZ_A2f  = (size_t)DINNER*DSTATE*4;
    const size_t SZ_states = (size_t)BATCH*NCHUNK*DSTATE*DINNER*2;
    const size_t SZ_dtsum  = (size_t)BATCH*NCHUNK*DINNER*4;

    size_t off = 0;
    auto take = [&](size_t bytes)->char*{ char* p = ws + off; off += (bytes + 255) & ~(size_t)255; return p; };

    char* regA = take(SZ_regA);
    u16*  hb   = (u16*)regA;
    u16*  wib  = (u16*)(regA + SZ_hb);
    u16*  wdtb = (u16*)regA;                                  // after in_proj
    u16*  wob  = (u16*)(regA + ((SZ_wdtb + 255) & ~(size_t)255));
    u16*  xb   = (u16*)take(SZ_big);                          // x; Y(partial0) aliases after conv
    u16*  zb   = (u16*)take(SZ_big);
    u16*  ub   = (u16*)take(SZ_big);
    u16*  Yp1  = (u16*)take(SZ_big);                          // partial1
    float* xpf = (float*)take(SZ_xpf);
    float* dtv = (float*)take(SZ_dtv);
    u32*  A2v  = (u32*)take(SZ_A2);
    float* A2f = (float*)take(SZ_A2f);
    u16*  states = (u16*)take(SZ_states);
    float* dtsum  = (float*)take(SZ_dtsum);
    u16*  Y    = xb;
    if (off > ws_size) return;

    { int n = NROWS*DMODEL;       cast_k<<<dim3((n/8+255)/256), dim3(256), 0, stream>>>(hidden, hb, n); }
    { int n = 2*DINNER*DMODEL;    cast_k<<<dim3((n/8+255)/256), dim3(256), 0, stream>>>(w_in, wib, n); }
    a2pack_k<<<dim3(DINNER*8/256), dim3(256), 0, stream>>>(A_log, A2v);
    a2packf_k<<<dim3(DINNER*DSTATE/256), dim3(256), 0, stream>>>(A_log, A2f);

    gemm128_k<<<dim3((2*DINNER)/128, NROWS/128), dim3(256), 0, stream>>>(hb, wib, nullptr, xb, zb, DINNER, NROWS, 2*DINNER, DMODEL);

    { int n = DTN*DINNER;         cast_k<<<dim3((n/8+255)/256), dim3(256), 0, stream>>>(w_dt, wdtb, n); }
    { int n = DMODEL*DINNER;      cast_k<<<dim3((n/8+255)/256), dim3(256), 0, stream>>>(w_out, wob, n); }

    conv2_k<<<dim3(NROWS/8), dim3(256), 0, stream>>>(xb, conv_w, conv_b, ub);
    xpinit_k<<<dim3((NROWS*DTN + 255)/256), dim3(256), 0, stream>>>(xpf, b_dt);
    gemmsk_k<<<dim3((DTN+63)/64, NROWS/64, 4), dim3(256), 0, stream>>>(ub, wdtb, xpf, NROWS, DTN, DINNER, DINNER/4);
    dtv_k<<<dim3(NROWS*16/256), dim3(256), 0, stream>>>(xpf, dt_bias, dtv);

    scanA11_k<<<dim3(BATCH*NCHUNK*16), dim3(256), 0, stream>>>(ub, dtv, xpf, A2f, states, dtsum);
    scanB8_k<<<dim3(BATCH*DSTATE*DINNER/256), dim3(256), 0, stream>>>(states, dtsum, A2v);
    scanC12_k<<<dim3(BATCH*NCHUNK*16), dim3(256), 0, stream>>>(ub, dtv, xpf, A2f, states, Y, Yp1);

    gatenorm2_k<<<dim3(NROWS), dim3(256), 0, stream>>>(Y, Yp1, ub, Dv, zb, norm_w, norm_b);
    gemm128_k<<<dim3(DMODEL/128, NROWS/128), dim3(256), 0, stream>>>(Y, wob, (float*)d_out, nullptr, nullptr, 0, NROWS, DMODEL, DINNER);
}